// Round 10
// baseline (946.423 us; speedup 1.0000x reference)
//
#include <hip/hip_runtime.h>
#include <math.h>

// ToxicityGATv2 — round 10: gemm_mfma rebuilt — persistent LDS-resident B
// (split-column even/odd blocks), shfl-pair epilogue (no LDS round-trip, no
// waitcnt drains), ping-pong xn buffers. agg_csr untouched (proven body).

constexpr int N_ = 50000;
constexpr int E_ = 400000;
constexpr int G_ = 2000;
constexpr int H_ = 128;
constexpr int IN_ = 39;
constexpr int NT_ = (N_ + 63) / 64;  // 782 row tiles

typedef __attribute__((ext_vector_type(8))) short bf16x8;
typedef __attribute__((ext_vector_type(4))) float f32x4;

// ---------------- bf16 pack/unpack (RNE) ----------------
__device__ __forceinline__ unsigned pk_bf16(float a, float b) {
  unsigned ua = __float_as_uint(a);
  unsigned ub = __float_as_uint(b);
  ua = (ua + 0x7fffu + ((ua >> 16) & 1u)) >> 16;
  ub = (ub + 0x7fffu + ((ub >> 16) & 1u)) & 0xffff0000u;
  return ua | ub;
}
__device__ __forceinline__ unsigned short bf16_1(float x) {
  unsigned u = __float_as_uint(x);
  u = (u + 0x7fffu + ((u >> 16) & 1u)) >> 16;
  return (unsigned short)u;
}
__device__ __forceinline__ float up_lo(unsigned u) { return __uint_as_float(u << 16); }
__device__ __forceinline__ float up_hi(unsigned u) { return __uint_as_float(u & 0xffff0000u); }

// ---------------- histogram ----------------
__global__ __launch_bounds__(256) void hist_kernel(const int* __restrict__ keys, int n,
                                                   int* __restrict__ cnt) {
  for (int i = blockIdx.x * 256 + threadIdx.x; i < n; i += gridDim.x * 256)
    atomicAdd(&cnt[keys[i]], 1);
}

// ---------------- multi-block scan ----------------
__global__ __launch_bounds__(1024) void scan_local(const int* __restrict__ in,
                                                   int* __restrict__ outx,
                                                   int* __restrict__ bsum, int n) {
  __shared__ int wsum[16];
  int t = threadIdx.x, lane = t & 63, wid = t >> 6;
  int idx = blockIdx.x * 1024 + t;
  int v = (idx < n) ? in[idx] : 0;
  int x = v;
#pragma unroll
  for (int off = 1; off < 64; off <<= 1) {
    int y = __shfl_up(x, off, 64);
    if (lane >= off) x += y;
  }
  if (lane == 63) wsum[wid] = x;
  __syncthreads();
  if (t == 0) {
    int acc = 0;
#pragma unroll
    for (int w = 0; w < 16; w++) { int tmp = wsum[w]; wsum[w] = acc; acc += tmp; }
    bsum[blockIdx.x] = acc;
  }
  __syncthreads();
  if (idx < n) outx[idx] = wsum[wid] + x - v;
}

__global__ __launch_bounds__(64) void scan_bsum(const int* __restrict__ bsum,
                                                int* __restrict__ boff, int nb) {
  int t = threadIdx.x;
  int v = (t < nb) ? bsum[t] : 0;
  int x = v;
#pragma unroll
  for (int off = 1; off < 64; off <<= 1) {
    int y = __shfl_up(x, off, 64);
    if (t >= off) x += y;
  }
  boff[t] = x - v;
}

__global__ __launch_bounds__(1024) void scan_add(int* __restrict__ eoff,
                                                 const int* __restrict__ boff,
                                                 int* __restrict__ cursor, int n) {
  int idx = blockIdx.x * 1024 + threadIdx.x;
  if (idx < n) {
    int e = eoff[idx] + boff[idx >> 10];
    eoff[idx] = e;
    cursor[idx] = e;
  }
  if (idx == 0) eoff[n] = E_;
}

// ---------------- goff from sorted batch ----------------
__global__ __launch_bounds__(256) void goff_from_sorted(const int* __restrict__ batch,
                                                        int* __restrict__ goff) {
  int i = blockIdx.x * 256 + threadIdx.x;
  if (i >= N_) return;
  int bi = batch[i];
  int bp = (i == 0) ? -1 : batch[i - 1];
  for (int g = bp + 1; g <= bi; g++) goff[g] = i;
  if (i == N_ - 1) {
    for (int g = bi + 1; g <= G_; g++) goff[g] = N_;
  }
}

// ---------------- edge scatter (bf16 attrs) ----------------
__global__ __launch_bounds__(256) void edge_scatter(const int* __restrict__ ei,
                                                    const float* __restrict__ ea,
                                                    int* __restrict__ cursor,
                                                    int* __restrict__ esrc,
                                                    unsigned* __restrict__ easb) {
  int e = blockIdx.x * 256 + threadIdx.x;
  if (e >= E_) return;
  int src = ei[e];
  int dst = ei[E_ + e];
  int j = atomicAdd(&cursor[dst], 1);
  esrc[j] = src;
  const float4* eav = (const float4*)(ea + (size_t)e * 8);
  float4 a0 = eav[0], a1 = eav[1];
  uint4 o;
  o.x = pk_bf16(a0.x, a0.y);
  o.y = pk_bf16(a0.z, a0.w);
  o.z = pk_bf16(a1.x, a1.y);
  o.w = pk_bf16(a1.z, a1.w);
  ((uint4*)easb)[j] = o;
}

// ---------------- weight pre-pack: wpack[l][n][k] = bf16([Wl|Wr][k][n]) -------
__global__ __launch_bounds__(256) void pack_weights(const float* __restrict__ Wl,
                                                    const float* __restrict__ Wr,
                                                    unsigned short* __restrict__ wpack) {
  int i = blockIdx.x * 256 + threadIdx.x;
  if (i >= 3 * 128 * 256) return;
  int l = i >> 15;
  int rem = i & 32767;
  int k = rem >> 8;
  int n = rem & 255;
  const float* Wsrc = (n < 128) ? (Wl + l * H_ * H_) : (Wr + l * H_ * H_);
  int nn = n & 127;
  wpack[(size_t)l * 32768 + n * 128 + k] = bf16_1(Wsrc[k * H_ + nn]);
}

// ---------------- input GEMM + fused colstats ----------------
__global__ __launch_bounds__(256) void in_gemm(const float* __restrict__ x,
                                               const float* __restrict__ W,
                                               const float* __restrict__ b,
                                               float* __restrict__ y,
                                               float* __restrict__ ssum,
                                               float* __restrict__ ssq) {
  __shared__ float xs[32][40];
  __shared__ float s1[256], s2[256];
  int t = threadIdx.x;
  int row0 = blockIdx.x * 32;
  for (int i = t; i < 32 * IN_; i += 256) {
    int r = i / IN_, k = i % IN_;
    int row = row0 + r;
    xs[r][k] = (row < N_) ? x[row * IN_ + k] : 0.f;
  }
  __syncthreads();
  int col = t & 127;
  int half = t >> 7;
  float acc[16];
#pragma unroll
  for (int r = 0; r < 16; r++) acc[r] = 0.f;
  for (int k = 0; k < IN_; k++) {
    float w = W[k * H_ + col];
#pragma unroll
    for (int r = 0; r < 16; r++) acc[r] = fmaf(xs[half * 16 + r][k], w, acc[r]);
  }
  float bb = b[col];
  float a1 = 0.f, a2 = 0.f;
#pragma unroll
  for (int r = 0; r < 16; r++) {
    int row = row0 + half * 16 + r;
    float v = acc[r] + bb;
    if (row < N_) {
      y[row * H_ + col] = v;
      a1 += v;
      a2 = fmaf(v, v, a2);
    }
  }
  s1[t] = a1; s2[t] = a2;
  __syncthreads();
  if (t < 128) {
    atomicAdd(&ssum[t], s1[t] + s1[t + 128]);
    atomicAdd(&ssq[t], s2[t] + s2[t + 128]);
  }
}

// ---------------- MFMA node GEMM v2 ----------
// Even blocks: B=Wl -> xlb, and own the xn_out update. Odd blocks: B=Wr -> xrb.
// B (128 cols x 128 k, bf16) LDS-resident, staged once; grid-stride row tiles.
// MODE 1: v=relu(bn(buf)).  MODE 2: v=xn_in+elu(bn(buf)).  type0 writes xn_out.
template <int MODE>
__global__ __launch_bounds__(256) void gemm_mfma(const float* __restrict__ xn_in,
                                                 float* __restrict__ xn_out,
                                                 const float* __restrict__ buf,
                                                 const float* __restrict__ g,
                                                 const float* __restrict__ beta,
                                                 const float* __restrict__ ssum,
                                                 const float* __restrict__ ssq,
                                                 float rows_inv,
                                                 const unsigned short* __restrict__ wp,
                                                 unsigned* __restrict__ xlb,
                                                 unsigned* __restrict__ xrb) {
  __shared__ short a_s[64][136];   // 17408 B: 64 rows x 128 k
  __shared__ short b_s[128][136];  // 34816 B: 128 n x 128 k
  int t = threadIdx.x;
  int lane = t & 63, w = t >> 6;
  int quad = lane >> 4, lc = lane & 15;
  int type = blockIdx.x & 1;
  unsigned* xout = type ? xrb : xlb;

  // ---- stage B once (32 KB from pre-packed weights) ----
  {
    const unsigned short* wbase = wp + (size_t)type * 16384;
    int nl = t >> 1;
    int kh = (t & 1) * 64;
#pragma unroll
    for (int v4 = 0; v4 < 8; v4++)
      *(uint4*)&b_s[nl][kh + v4 * 8] = *(const uint4*)&wbase[nl * 128 + kh + v4 * 8];
  }

  int stride = gridDim.x >> 1;
  for (int tile = blockIdx.x >> 1; tile < NT_; tile += stride) {
    int row0 = tile * 64;
    __syncthreads();  // prior MFMA reads of a_s done; B-stage visible (1st iter)
    // ---- stage A (fused BN epilogue, bf16 into LDS) ----
    {
      int r = t >> 2;
      int row = row0 + r;
      int kb0 = (t & 3) * 32;
      bool valid = row < N_;
      for (int kk = 0; kk < 32; kk += 4) {
        int c = kb0 + kk;
        float4 v = make_float4(0.f, 0.f, 0.f, 0.f);
        if (valid) {
          float4 bv = *(const float4*)&buf[(size_t)row * H_ + c];
          float4 gv = *(const float4*)&g[c];
          float4 be = *(const float4*)&beta[c];
          float4 s1 = *(const float4*)&ssum[c];
          float4 s2 = *(const float4*)&ssq[c];
          float m0 = s1.x * rows_inv, m1 = s1.y * rows_inv;
          float m2 = s1.z * rows_inv, m3 = s1.w * rows_inv;
          float r0 = rsqrtf(s2.x * rows_inv - m0 * m0 + 1e-5f);
          float r1 = rsqrtf(s2.y * rows_inv - m1 * m1 + 1e-5f);
          float r2 = rsqrtf(s2.z * rows_inv - m2 * m2 + 1e-5f);
          float r3 = rsqrtf(s2.w * rows_inv - m3 * m3 + 1e-5f);
          float t0 = gv.x * (bv.x - m0) * r0 + be.x;
          float t1 = gv.y * (bv.y - m1) * r1 + be.y;
          float t2 = gv.z * (bv.z - m2) * r2 + be.z;
          float t3 = gv.w * (bv.w - m3) * r3 + be.w;
          if (MODE == 1) {
            v = make_float4(fmaxf(t0, 0.f), fmaxf(t1, 0.f), fmaxf(t2, 0.f), fmaxf(t3, 0.f));
          } else {
            float4 xo = *(const float4*)&xn_in[(size_t)row * H_ + c];
            v.x = xo.x + ((t0 > 0.f) ? t0 : (__expf(t0) - 1.f));
            v.y = xo.y + ((t1 > 0.f) ? t1 : (__expf(t1) - 1.f));
            v.z = xo.z + ((t2 > 0.f) ? t2 : (__expf(t2) - 1.f));
            v.w = xo.w + ((t3 > 0.f) ? t3 : (__expf(t3) - 1.f));
          }
          if (type == 0) *(float4*)&xn_out[(size_t)row * H_ + c] = v;
        }
        uint2 pk;
        pk.x = pk_bf16(v.x, v.y);
        pk.y = pk_bf16(v.z, v.w);
        *(uint2*)&a_s[r][c] = pk;
      }
    }
    __syncthreads();

    // ---- MFMA: 64 rows x 128 cols ----
    f32x4 acc[8];
#pragma unroll
    for (int nt = 0; nt < 8; nt++) acc[nt] = (f32x4){0.f, 0.f, 0.f, 0.f};
#pragma unroll
    for (int kb = 0; kb < 4; kb++) {
      bf16x8 av = *(const bf16x8*)&a_s[w * 16 + lc][kb * 32 + quad * 8];
#pragma unroll
      for (int nt = 0; nt < 8; nt++) {
        bf16x8 bv = *(const bf16x8*)&b_s[nt * 16 + lc][kb * 32 + quad * 8];
        acc[nt] = __builtin_amdgcn_mfma_f32_16x16x32_bf16(av, bv, acc[nt], 0, 0, 0);
      }
    }

    // ---- epilogue: shfl-pair pack, direct stores (no LDS) ----
    int rowg0 = row0 + w * 16 + quad * 4;
#pragma unroll
    for (int nt = 0; nt < 8; nt++) {
#pragma unroll
      for (int rr = 0; rr < 4; rr++) {
        float v = acc[nt][rr];
        float pv = __shfl_xor(v, 1, 64);
        int rowg = rowg0 + rr;
        if (!(lc & 1) && rowg < N_) {
          unsigned u = pk_bf16(v, pv);
          xout[(size_t)rowg * 64 + nt * 8 + (lc >> 1)] = u;
        }
      }
    }
  }
}

// ---------------- CSR aggregation (round-5 proven body) ----------------
__device__ __forceinline__ float ep8u(const uint4& u, const float* w) {
  float ep = up_lo(u.x) * w[0];
  ep = fmaf(up_hi(u.x), w[1], ep);
  ep = fmaf(up_lo(u.y), w[2], ep);
  ep = fmaf(up_hi(u.y), w[3], ep);
  ep = fmaf(up_lo(u.z), w[4], ep);
  ep = fmaf(up_hi(u.z), w[5], ep);
  ep = fmaf(up_lo(u.w), w[6], ep);
  ep = fmaf(up_hi(u.w), w[7], ep);
  return ep;
}

__global__ __launch_bounds__(256) void agg_csr(const int* __restrict__ eoff,
                                               const int* __restrict__ esrc,
                                               const unsigned* __restrict__ easb,
                                               const float* __restrict__ Wel,
                                               const float* __restrict__ attl,
                                               const unsigned* __restrict__ xlb,
                                               const unsigned* __restrict__ xrb,
                                               const float* __restrict__ cb,
                                               float* __restrict__ buf,
                                               float* __restrict__ ssum,
                                               float* __restrict__ ssq) {
  __shared__ float sA[256], sB[256], sC[256], sD[256];
  int t = threadIdx.x;
  int l = t & 63;
  int sub = t >> 6;
  int c0 = l * 2;
  float w0[8], w1[8];
#pragma unroll
  for (int k = 0; k < 8; k++) {
    float2 wv = *(const float2*)&Wel[k * H_ + c0];
    w0[k] = wv.x; w1[k] = wv.y;
  }
  float2 attv = *(const float2*)&attl[c0];
  float2 cbv = *(const float2*)&cb[c0];
  const uint4* eas4 = (const uint4*)easb;
  float a1_0 = 0.f, a1_1 = 0.f, a2_0 = 0.f, a2_1 = 0.f;
  for (int n = blockIdx.x * 4 + sub; n < N_; n += gridDim.x * 4) {
    unsigned xru = xrb[(size_t)n * 64 + l];
    float xr0 = up_lo(xru), xr1 = up_hi(xru);
    int e0 = eoff[n], e1 = eoff[n + 1];
    float acc0 = 0.f, acc1 = 0.f, den = 0.f;
    int j = e0;
    for (; j + 4 <= e1; j += 4) {
      int s0 = esrc[j], s1 = esrc[j + 1], s2 = esrc[j + 2], s3 = esrc[j + 3];
      uint4 u0 = eas4[j], u1 = eas4[j + 1], u2 = eas4[j + 2], u3 = eas4[j + 3];
      unsigned xu0 = xlb[(size_t)s0 * 64 + l];
      unsigned xu1 = xlb[(size_t)s1 * 64 + l];
      unsigned xu2 = xlb[(size_t)s2 * 64 + l];
      unsigned xu3 = xlb[(size_t)s3 * 64 + l];
      float x00 = up_lo(xu0), x01 = up_hi(xu0);
      float x10 = up_lo(xu1), x11 = up_hi(xu1);
      float x20 = up_lo(xu2), x21 = up_hi(xu2);
      float x30 = up_lo(xu3), x31 = up_hi(xu3);
      float m00 = x00 + xr0 + ep8u(u0, w0);
      float m01 = x01 + xr1 + ep8u(u0, w1);
      float m10 = x10 + xr0 + ep8u(u1, w0);
      float m11 = x11 + xr1 + ep8u(u1, w1);
      float m20 = x20 + xr0 + ep8u(u2, w0);
      float m21 = x21 + xr1 + ep8u(u2, w1);
      float m30 = x30 + xr0 + ep8u(u3, w0);
      float m31 = x31 + xr1 + ep8u(u3, w1);
      m00 = (m00 > 0.f) ? m00 : 0.2f * m00;
      m01 = (m01 > 0.f) ? m01 : 0.2f * m01;
      m10 = (m10 > 0.f) ? m10 : 0.2f * m10;
      m11 = (m11 > 0.f) ? m11 : 0.2f * m11;
      m20 = (m20 > 0.f) ? m20 : 0.2f * m20;
      m21 = (m21 > 0.f) ? m21 : 0.2f * m21;
      m30 = (m30 > 0.f) ? m30 : 0.2f * m30;
      m31 = (m31 > 0.f) ? m31 : 0.2f * m31;
      float p0 = fmaf(m00, attv.x, m01 * attv.y);
      float p1 = fmaf(m10, attv.x, m11 * attv.y);
      float p2 = fmaf(m20, attv.x, m21 * attv.y);
      float p3 = fmaf(m30, attv.x, m31 * attv.y);
#pragma unroll
      for (int off = 8; off > 0; off >>= 1) {
        p0 += __shfl_xor(p0, off, 64);
        p1 += __shfl_xor(p1, off, 64);
        p2 += __shfl_xor(p2, off, 64);
        p3 += __shfl_xor(p3, off, 64);
      }
      float e0v = __expf(p0), e1v = __expf(p1), e2v = __expf(p2), e3v = __expf(p3);
      acc0 = fmaf(e0v, x00, acc0); acc1 = fmaf(e0v, x01, acc1);
      acc0 = fmaf(e1v, x10, acc0); acc1 = fmaf(e1v, x11, acc1);
      acc0 = fmaf(e2v, x20, acc0); acc1 = fmaf(e2v, x21, acc1);
      acc0 = fmaf(e3v, x30, acc0); acc1 = fmaf(e3v, x31, acc1);
      den += (e0v + e1v) + (e2v + e3v);
    }
    for (; j < e1; j++) {
      int s0 = esrc[j];
      uint4 u0 = eas4[j];
      unsigned xu0 = xlb[(size_t)s0 * 64 + l];
      float x00 = up_lo(xu0), x01 = up_hi(xu0);
      float m00 = x00 + xr0 + ep8u(u0, w0);
      float m01 = x01 + xr1 + ep8u(u0, w1);
      m00 = (m00 > 0.f) ? m00 : 0.2f * m00;
      m01 = (m01 > 0.f) ? m01 : 0.2f * m01;
      float p0 = fmaf(m00, attv.x, m01 * attv.y);
#pragma unroll
      for (int off = 8; off > 0; off >>= 1) p0 += __shfl_xor(p0, off, 64);
      float e0v = __expf(p0);
      acc0 = fmaf(e0v, x00, acc0);
      acc1 = fmaf(e0v, x01, acc1);
      den += e0v;
    }
    float inv = 1.f / (den + 1e-16f);
    float h0 = acc0 * inv + cbv.x;
    float h1 = acc1 * inv + cbv.y;
    *(float2*)&buf[(size_t)n * H_ + c0] = make_float2(h0, h1);
    a1_0 += h0; a1_1 += h1;
    a2_0 = fmaf(h0, h0, a2_0); a2_1 = fmaf(h1, h1, a2_1);
  }
  sA[t] = a1_0; sB[t] = a1_1; sC[t] = a2_0; sD[t] = a2_1;
  __syncthreads();
  if (t < 64) {
    float r1 = sA[t] + sA[t + 64] + sA[t + 128] + sA[t + 192];
    float r2 = sB[t] + sB[t + 64] + sB[t + 128] + sB[t + 192];
    float r3 = sC[t] + sC[t + 64] + sC[t + 128] + sC[t + 192];
    float r4 = sD[t] + sD[t + 64] + sD[t + 128] + sD[t + 192];
    atomicAdd(&ssum[2 * t], r1);
    atomicAdd(&ssum[2 * t + 1], r2);
    atomicAdd(&ssq[2 * t], r3);
    atomicAdd(&ssq[2 * t + 1], r4);
  }
}

// ---------------- BN apply with inline finalize ----------------
__global__ __launch_bounds__(256) void apply_bn_relu(const float* __restrict__ y,
                                                     float* __restrict__ out,
                                                     const float* __restrict__ g,
                                                     const float* __restrict__ beta,
                                                     const float* __restrict__ ssum,
                                                     const float* __restrict__ ssq,
                                                     float rows_inv,
                                                     long total, int cmask) {
  long i = (long)blockIdx.x * 256 + threadIdx.x;
  if (i >= total) return;
  int c = (int)i & cmask;
  float m = ssum[c] * rows_inv;
  float rs = rsqrtf(ssq[c] * rows_inv - m * m + 1e-5f);
  float v = g[c] * (y[i] - m) * rs + beta[c];
  out[i] = fmaxf(v, 0.f);
}

// ---------------- pooling with fused layer-2 residual (inline BN finalize) ----
__global__ __launch_bounds__(128) void pool_residual(const int* __restrict__ goff,
                                                     const float* __restrict__ xn,
                                                     const float* __restrict__ buf,
                                                     const float* __restrict__ g,
                                                     const float* __restrict__ beta,
                                                     const float* __restrict__ ssum,
                                                     const float* __restrict__ ssq,
                                                     float rows_inv,
                                                     float* __restrict__ xg) {
  int gr = blockIdx.x;
  int t = threadIdx.x;
  int n0 = goff[gr], n1 = goff[gr + 1];
  float mm = ssum[t] * rows_inv;
  float rr = rsqrtf(ssq[t] * rows_inv - mm * mm + 1e-5f);
  float gg = g[t], bb = beta[t];
  float s = 0.f, mx = -INFINITY;
  for (int n = n0; n < n1; n++) {
    float w = gg * (buf[(size_t)n * H_ + t] - mm) * rr + bb;
    w = (w > 0.f) ? w : (__expf(w) - 1.f);
    float v = xn[(size_t)n * H_ + t] + w;
    s += v;
    mx = fmaxf(mx, v);
  }
  float c = (float)(n1 - n0);
  xg[gr * 384 + t] = s / fmaxf(c, 1.f);
  xg[gr * 384 + 128 + t] = (c > 0.f) ? mx : 0.f;
  xg[gr * 384 + 256 + t] = s;
}

// ---------------- MLP GEMMs (fused colstats) ----------------
template <int K, int COLS>
__global__ void mlp_gemm(const float* __restrict__ A, const float* __restrict__ W,
                         const float* __restrict__ b, float* __restrict__ Y, int rows,
                         float* __restrict__ ssum, float* __restrict__ ssq) {
  __shared__ float xs[8][K];
  int t = threadIdx.x;
  int row0 = blockIdx.x * 8;
  for (int i = t; i < 8 * K; i += COLS) {
    int r = i / K, k = i % K;
    int row = row0 + r;
    xs[r][k] = (row < rows) ? A[row * K + k] : 0.f;
  }
  __syncthreads();
  float acc[8];
#pragma unroll
  for (int r = 0; r < 8; r++) acc[r] = 0.f;
  for (int k = 0; k < K; k++) {
    float w = W[k * COLS + t];
#pragma unroll
    for (int r = 0; r < 8; r++) acc[r] = fmaf(xs[r][k], w, acc[r]);
  }
  float bb = b[t];
  float a1 = 0.f, a2 = 0.f;
#pragma unroll
  for (int r = 0; r < 8; r++) {
    int row = row0 + r;
    if (row < rows) {
      float v = acc[r] + bb;
      Y[row * COLS + t] = v;
      a1 += v;
      a2 = fmaf(v, v, a2);
    }
  }
  atomicAdd(&ssum[t], a1);
  atomicAdd(&ssq[t], a2);
}

// ---------------- head ----------------
__global__ __launch_bounds__(64) void head_kernel(const float* __restrict__ u,
                                                  const float* __restrict__ W,
                                                  const float* __restrict__ b,
                                                  float* __restrict__ out) {
  __shared__ float row[128];
  int g = blockIdx.x;
  int t = threadIdx.x;
  row[t] = u[g * 128 + t];
  row[t + 64] = u[g * 128 + 64 + t];
  __syncthreads();
  if (t < 12) {
    float acc = b[t];
    for (int k = 0; k < 128; k++) acc = fmaf(row[k], W[k * 12 + t], acc);
    out[g * 12 + t] = 1.f / (1.f + expf(-acc));
  }
}

// ---------------- launcher ----------------
extern "C" void kernel_launch(void* const* d_in, const int* in_sizes, int n_in, void* d_out,
                              int out_size, void* d_ws, size_t ws_size, hipStream_t stream) {
  (void)in_sizes; (void)n_in; (void)out_size; (void)ws_size;
  const float* x       = (const float*)d_in[0];
  const int*   ei      = (const int*)d_in[1];
  const float* ea      = (const float*)d_in[2];
  const int*   batch   = (const int*)d_in[3];
  const float* in_W    = (const float*)d_in[4];
  const float* in_b    = (const float*)d_in[5];
  const float* in_g    = (const float*)d_in[6];
  const float* in_beta = (const float*)d_in[7];
  const float* Wl      = (const float*)d_in[8];
  const float* Wr      = (const float*)d_in[9];
  const float* We      = (const float*)d_in[10];
  const float* att     = (const float*)d_in[11];
  const float* conv_b  = (const float*)d_in[12];
  const float* bn_g    = (const float*)d_in[13];
  const float* bn_b    = (const float*)d_in[14];
  const float* t1_W    = (const float*)d_in[15];
  const float* t1_b    = (const float*)d_in[16];
  const float* t1_g    = (const float*)d_in[17];
  const float* t1_beta = (const float*)d_in[18];
  const float* t2_W    = (const float*)d_in[19];
  const float* t2_b    = (const float*)d_in[20];
  const float* t2_g    = (const float*)d_in[21];
  const float* t2_beta = (const float*)d_in[22];
  const float* head_W  = (const float*)d_in[23];
  const float* head_b  = (const float*)d_in[24];
  float* out = (float*)d_out;

  float* p = (float*)d_ws;
  float* xnA   = p; p += N_ * H_;
  float* xnB   = p; p += N_ * H_;
  float* buf   = p; p += N_ * H_;
  float* sstat = p; p += 6 * 512;   // 6 stages x (ssum 256 | ssq 256)
  float* xg    = p; p += G_ * 384;
  float* u1    = p; p += G_ * 256;
  float* u2    = p; p += G_ * 128;
  unsigned* up = (unsigned*)p;
  unsigned* xlb  = up; up += (size_t)N_ * 64;
  unsigned* xrb  = up; up += (size_t)N_ * 64;
  unsigned* easb = up; up += (size_t)E_ * 4;
  unsigned short* wpack = (unsigned short*)up; up += 3 * 32768 / 2;
  int* ip = (int*)up;
  int* deg    = ip; ip += N_;
  int* eoff   = ip; ip += N_ + 1;
  int* cursor = ip; ip += N_;
  int* goff   = ip; ip += G_ + 1;
  int* esrc   = ip; ip += E_;
  int* bsum   = ip; ip += 64;
  int* boff   = ip; ip += 64;

#define SSUM(s) (sstat + (s) * 512)
#define SSQ(s)  (sstat + (s) * 512 + 256)

  // ---- build CSR structures + pre-pack weights ----
  hipMemsetAsync(deg, 0, (size_t)N_ * sizeof(int), stream);
  hipMemsetAsync(sstat, 0, 6 * 512 * sizeof(float), stream);
  hist_kernel<<<1024, 256, 0, stream>>>(ei + E_, E_, deg);
  scan_local<<<49, 1024, 0, stream>>>(deg, eoff, bsum, N_);
  scan_bsum<<<1, 64, 0, stream>>>(bsum, boff, 49);
  scan_add<<<49, 1024, 0, stream>>>(eoff, boff, cursor, N_);
  edge_scatter<<<(E_ + 255) / 256, 256, 0, stream>>>(ei, ea, cursor, esrc, easb);
  goff_from_sorted<<<(N_ + 255) / 256, 256, 0, stream>>>(batch, goff);
  pack_weights<<<384, 256, 0, stream>>>(Wl, Wr, wpack);

  // ---- input layer (stats -> stage 0) ----
  in_gemm<<<(N_ + 31) / 32, 256, 0, stream>>>(x, in_W, in_b, buf, SSUM(0), SSQ(0));

  // ---- 3 GATv2 layers; xn ping-pong: l0 -> xnA, l1 -> xnB, l2 -> xnA ----
  const float rnInv = 1.f / N_;
  gemm_mfma<1><<<768, 256, 0, stream>>>(xnA, xnA, buf, in_g, in_beta, SSUM(0), SSQ(0), rnInv,
                                        wpack, xlb, xrb);
  agg_csr<<<2048, 256, 0, stream>>>(eoff, esrc, easb, We, att, xlb, xrb, conv_b,
                                    buf, SSUM(1), SSQ(1));
  gemm_mfma<2><<<768, 256, 0, stream>>>(xnA, xnB, buf, bn_g, bn_b, SSUM(1), SSQ(1), rnInv,
                                        wpack + 32768, xlb, xrb);
  agg_csr<<<2048, 256, 0, stream>>>(eoff, esrc, easb, We + 8 * H_, att + H_, xlb, xrb,
                                    conv_b + H_, buf, SSUM(2), SSQ(2));
  gemm_mfma<2><<<768, 256, 0, stream>>>(xnB, xnA, buf, bn_g + H_, bn_b + H_, SSUM(2), SSQ(2),
                                        rnInv, wpack + 65536, xlb, xrb);
  agg_csr<<<2048, 256, 0, stream>>>(eoff, esrc, easb, We + 16 * H_, att + 2 * H_, xlb, xrb,
                                    conv_b + 2 * H_, buf, SSUM(3), SSQ(3));

  // ---- pooling with fused layer-2 residual (stage 3 stats) ----
  pool_residual<<<G_, 128, 0, stream>>>(goff, xnA, buf, bn_g + 2 * H_, bn_b + 2 * H_,
                                        SSUM(3), SSQ(3), rnInv, xg);

  // ---- t1 (stats -> stage 4) ----
  const float rgInv = 1.f / G_;
  mlp_gemm<384, 256><<<G_ / 8, 256, 0, stream>>>(xg, t1_W, t1_b, u1, G_, SSUM(4), SSQ(4));
  apply_bn_relu<<<(G_ * 256 + 255) / 256, 256, 0, stream>>>(u1, u1, t1_g, t1_beta,
                                                            SSUM(4), SSQ(4), rgInv,
                                                            (long)G_ * 256, 255);

  // ---- t2 (stats -> stage 5) ----
  mlp_gemm<256, 128><<<G_ / 8, 128, 0, stream>>>(u1, t2_W, t2_b, u2, G_, SSUM(5), SSQ(5));
  apply_bn_relu<<<(G_ * 128 + 255) / 256, 256, 0, stream>>>(u2, u2, t2_g, t2_beta,
                                                            SSUM(5), SSQ(5), rgInv,
                                                            (long)G_ * 128, 127);

  // ---- head ----
  head_kernel<<<G_, 64, 0, stream>>>(u2, head_W, head_b, out);
#undef SSUM
#undef SSQ
}

// Round 11
// 919.915 us; speedup vs baseline: 1.0288x; 1.0288x over previous
//
#include <hip/hip_runtime.h>
#include <math.h>

// ToxicityGATv2 — round 11: gemm_mfma v3 — A staged once (round-9 structure,
// single xn buffer), B fragments loaded DIRECTLY from pre-packed global
// weights (L2-resident, no B-LDS staging, 1 barrier/block), shfl-pair
// epilogue (verified in r10). agg_csr untouched (proven body).

constexpr int N_ = 50000;
constexpr int E_ = 400000;
constexpr int G_ = 2000;
constexpr int H_ = 128;
constexpr int IN_ = 39;

typedef __attribute__((ext_vector_type(8))) short bf16x8;
typedef __attribute__((ext_vector_type(4))) float f32x4;

// ---------------- bf16 pack/unpack (RNE) ----------------
__device__ __forceinline__ unsigned pk_bf16(float a, float b) {
  unsigned ua = __float_as_uint(a);
  unsigned ub = __float_as_uint(b);
  ua = (ua + 0x7fffu + ((ua >> 16) & 1u)) >> 16;
  ub = (ub + 0x7fffu + ((ub >> 16) & 1u)) & 0xffff0000u;
  return ua | ub;
}
__device__ __forceinline__ unsigned short bf16_1(float x) {
  unsigned u = __float_as_uint(x);
  u = (u + 0x7fffu + ((u >> 16) & 1u)) >> 16;
  return (unsigned short)u;
}
__device__ __forceinline__ float up_lo(unsigned u) { return __uint_as_float(u << 16); }
__device__ __forceinline__ float up_hi(unsigned u) { return __uint_as_float(u & 0xffff0000u); }

// ---------------- histogram ----------------
__global__ __launch_bounds__(256) void hist_kernel(const int* __restrict__ keys, int n,
                                                   int* __restrict__ cnt) {
  for (int i = blockIdx.x * 256 + threadIdx.x; i < n; i += gridDim.x * 256)
    atomicAdd(&cnt[keys[i]], 1);
}

// ---------------- multi-block scan ----------------
__global__ __launch_bounds__(1024) void scan_local(const int* __restrict__ in,
                                                   int* __restrict__ outx,
                                                   int* __restrict__ bsum, int n) {
  __shared__ int wsum[16];
  int t = threadIdx.x, lane = t & 63, wid = t >> 6;
  int idx = blockIdx.x * 1024 + t;
  int v = (idx < n) ? in[idx] : 0;
  int x = v;
#pragma unroll
  for (int off = 1; off < 64; off <<= 1) {
    int y = __shfl_up(x, off, 64);
    if (lane >= off) x += y;
  }
  if (lane == 63) wsum[wid] = x;
  __syncthreads();
  if (t == 0) {
    int acc = 0;
#pragma unroll
    for (int w = 0; w < 16; w++) { int tmp = wsum[w]; wsum[w] = acc; acc += tmp; }
    bsum[blockIdx.x] = acc;
  }
  __syncthreads();
  if (idx < n) outx[idx] = wsum[wid] + x - v;
}

__global__ __launch_bounds__(64) void scan_bsum(const int* __restrict__ bsum,
                                                int* __restrict__ boff, int nb) {
  int t = threadIdx.x;
  int v = (t < nb) ? bsum[t] : 0;
  int x = v;
#pragma unroll
  for (int off = 1; off < 64; off <<= 1) {
    int y = __shfl_up(x, off, 64);
    if (t >= off) x += y;
  }
  boff[t] = x - v;
}

__global__ __launch_bounds__(1024) void scan_add(int* __restrict__ eoff,
                                                 const int* __restrict__ boff,
                                                 int* __restrict__ cursor, int n) {
  int idx = blockIdx.x * 1024 + threadIdx.x;
  if (idx < n) {
    int e = eoff[idx] + boff[idx >> 10];
    eoff[idx] = e;
    cursor[idx] = e;
  }
  if (idx == 0) eoff[n] = E_;
}

// ---------------- goff from sorted batch ----------------
__global__ __launch_bounds__(256) void goff_from_sorted(const int* __restrict__ batch,
                                                        int* __restrict__ goff) {
  int i = blockIdx.x * 256 + threadIdx.x;
  if (i >= N_) return;
  int bi = batch[i];
  int bp = (i == 0) ? -1 : batch[i - 1];
  for (int g = bp + 1; g <= bi; g++) goff[g] = i;
  if (i == N_ - 1) {
    for (int g = bi + 1; g <= G_; g++) goff[g] = N_;
  }
}

// ---------------- edge scatter (bf16 attrs) ----------------
__global__ __launch_bounds__(256) void edge_scatter(const int* __restrict__ ei,
                                                    const float* __restrict__ ea,
                                                    int* __restrict__ cursor,
                                                    int* __restrict__ esrc,
                                                    unsigned* __restrict__ easb) {
  int e = blockIdx.x * 256 + threadIdx.x;
  if (e >= E_) return;
  int src = ei[e];
  int dst = ei[E_ + e];
  int j = atomicAdd(&cursor[dst], 1);
  esrc[j] = src;
  const float4* eav = (const float4*)(ea + (size_t)e * 8);
  float4 a0 = eav[0], a1 = eav[1];
  uint4 o;
  o.x = pk_bf16(a0.x, a0.y);
  o.y = pk_bf16(a0.z, a0.w);
  o.z = pk_bf16(a1.x, a1.y);
  o.w = pk_bf16(a1.z, a1.w);
  ((uint4*)easb)[j] = o;
}

// ---------------- weight pre-pack: wpack[l][n][k] = bf16([Wl|Wr][k][n]) -------
__global__ __launch_bounds__(256) void pack_weights(const float* __restrict__ Wl,
                                                    const float* __restrict__ Wr,
                                                    unsigned short* __restrict__ wpack) {
  int i = blockIdx.x * 256 + threadIdx.x;
  if (i >= 3 * 128 * 256) return;
  int l = i >> 15;
  int rem = i & 32767;
  int k = rem >> 8;
  int n = rem & 255;
  const float* Wsrc = (n < 128) ? (Wl + l * H_ * H_) : (Wr + l * H_ * H_);
  int nn = n & 127;
  wpack[(size_t)l * 32768 + n * 128 + k] = bf16_1(Wsrc[k * H_ + nn]);
}

// ---------------- input GEMM + fused colstats ----------------
__global__ __launch_bounds__(256) void in_gemm(const float* __restrict__ x,
                                               const float* __restrict__ W,
                                               const float* __restrict__ b,
                                               float* __restrict__ y,
                                               float* __restrict__ ssum,
                                               float* __restrict__ ssq) {
  __shared__ float xs[32][40];
  __shared__ float s1[256], s2[256];
  int t = threadIdx.x;
  int row0 = blockIdx.x * 32;
  for (int i = t; i < 32 * IN_; i += 256) {
    int r = i / IN_, k = i % IN_;
    int row = row0 + r;
    xs[r][k] = (row < N_) ? x[row * IN_ + k] : 0.f;
  }
  __syncthreads();
  int col = t & 127;
  int half = t >> 7;
  float acc[16];
#pragma unroll
  for (int r = 0; r < 16; r++) acc[r] = 0.f;
  for (int k = 0; k < IN_; k++) {
    float w = W[k * H_ + col];
#pragma unroll
    for (int r = 0; r < 16; r++) acc[r] = fmaf(xs[half * 16 + r][k], w, acc[r]);
  }
  float bb = b[col];
  float a1 = 0.f, a2 = 0.f;
#pragma unroll
  for (int r = 0; r < 16; r++) {
    int row = row0 + half * 16 + r;
    float v = acc[r] + bb;
    if (row < N_) {
      y[row * H_ + col] = v;
      a1 += v;
      a2 = fmaf(v, v, a2);
    }
  }
  s1[t] = a1; s2[t] = a2;
  __syncthreads();
  if (t < 128) {
    atomicAdd(&ssum[t], s1[t] + s1[t + 128]);
    atomicAdd(&ssq[t], s2[t] + s2[t + 128]);
  }
}

// ---------------- MFMA node GEMM v3 ----------
// One 64-row tile per block. A staged once in LDS (bf16, fused BN epilogue,
// xn updated in place). B fragments read directly from global pre-packed
// weights (L2-resident). Shfl-pair epilogue, no LDS round-trip.
// MODE 1: v=relu(bn(buf)).  MODE 2: v=xn+elu(bn(buf)).
template <int MODE>
__global__ __launch_bounds__(256) void gemm_mfma(float* __restrict__ xn,
                                                 const float* __restrict__ buf,
                                                 const float* __restrict__ g,
                                                 const float* __restrict__ beta,
                                                 const float* __restrict__ ssum,
                                                 const float* __restrict__ ssq,
                                                 float rows_inv,
                                                 const unsigned short* __restrict__ wp,
                                                 unsigned* __restrict__ xlb,
                                                 unsigned* __restrict__ xrb) {
  __shared__ short a_s[64][136];  // 17408 B
  int t = threadIdx.x;
  int lane = t & 63, w = t >> 6;
  int quad = lane >> 4, lc = lane & 15;
  int row0 = blockIdx.x * 64;

  // ---- stage A (fused BN epilogue, bf16 into LDS, fp32 xn updated) ----
  {
    int r = t >> 2;
    int row = row0 + r;
    int kb0 = (t & 3) * 32;
    bool valid = row < N_;
    for (int kk = 0; kk < 32; kk += 4) {
      int c = kb0 + kk;
      float4 v = make_float4(0.f, 0.f, 0.f, 0.f);
      if (valid) {
        float4 bv = *(const float4*)&buf[(size_t)row * H_ + c];
        float4 gv = *(const float4*)&g[c];
        float4 be = *(const float4*)&beta[c];
        float4 s1 = *(const float4*)&ssum[c];
        float4 s2 = *(const float4*)&ssq[c];
        float m0 = s1.x * rows_inv, m1 = s1.y * rows_inv;
        float m2 = s1.z * rows_inv, m3 = s1.w * rows_inv;
        float r0 = rsqrtf(s2.x * rows_inv - m0 * m0 + 1e-5f);
        float r1 = rsqrtf(s2.y * rows_inv - m1 * m1 + 1e-5f);
        float r2 = rsqrtf(s2.z * rows_inv - m2 * m2 + 1e-5f);
        float r3 = rsqrtf(s2.w * rows_inv - m3 * m3 + 1e-5f);
        float t0 = gv.x * (bv.x - m0) * r0 + be.x;
        float t1 = gv.y * (bv.y - m1) * r1 + be.y;
        float t2 = gv.z * (bv.z - m2) * r2 + be.z;
        float t3 = gv.w * (bv.w - m3) * r3 + be.w;
        if (MODE == 1) {
          v = make_float4(fmaxf(t0, 0.f), fmaxf(t1, 0.f), fmaxf(t2, 0.f), fmaxf(t3, 0.f));
        } else {
          float4 xo = *(const float4*)&xn[(size_t)row * H_ + c];
          v.x = xo.x + ((t0 > 0.f) ? t0 : (__expf(t0) - 1.f));
          v.y = xo.y + ((t1 > 0.f) ? t1 : (__expf(t1) - 1.f));
          v.z = xo.z + ((t2 > 0.f) ? t2 : (__expf(t2) - 1.f));
          v.w = xo.w + ((t3 > 0.f) ? t3 : (__expf(t3) - 1.f));
        }
        *(float4*)&xn[(size_t)row * H_ + c] = v;
      }
      uint2 pk;
      pk.x = pk_bf16(v.x, v.y);
      pk.y = pk_bf16(v.z, v.w);
      *(uint2*)&a_s[r][c] = pk;
    }
  }
  __syncthreads();

  // ---- MFMA: 64 rows x 256 cols; B fragments straight from global (L2) ----
  f32x4 acc[16];
#pragma unroll
  for (int nt = 0; nt < 16; nt++) acc[nt] = (f32x4){0.f, 0.f, 0.f, 0.f};
#pragma unroll
  for (int kb = 0; kb < 4; kb++) {
    bf16x8 av = *(const bf16x8*)&a_s[w * 16 + lc][kb * 32 + quad * 8];
#pragma unroll
    for (int nt = 0; nt < 16; nt++) {
      bf16x8 bv = *(const bf16x8*)&wp[(size_t)(nt * 16 + lc) * 128 + kb * 32 + quad * 8];
      acc[nt] = __builtin_amdgcn_mfma_f32_16x16x32_bf16(av, bv, acc[nt], 0, 0, 0);
    }
  }

  // ---- epilogue: shfl-pair pack, direct stores (no LDS) ----
  int rowg0 = row0 + w * 16 + quad * 4;
#pragma unroll
  for (int nt = 0; nt < 16; nt++) {
    unsigned* xout = (nt < 8) ? xlb : xrb;
    int cp0 = (nt < 8) ? nt * 8 : (nt - 8) * 8;
#pragma unroll
    for (int rr = 0; rr < 4; rr++) {
      float v = acc[nt][rr];
      float pv = __shfl_xor(v, 1, 64);
      int rowg = rowg0 + rr;
      if (!(lc & 1) && rowg < N_) {
        unsigned u = pk_bf16(v, pv);
        xout[(size_t)rowg * 64 + cp0 + (lc >> 1)] = u;
      }
    }
  }
}

// ---------------- CSR aggregation (round-5 proven body) ----------------
__device__ __forceinline__ float ep8u(const uint4& u, const float* w) {
  float ep = up_lo(u.x) * w[0];
  ep = fmaf(up_hi(u.x), w[1], ep);
  ep = fmaf(up_lo(u.y), w[2], ep);
  ep = fmaf(up_hi(u.y), w[3], ep);
  ep = fmaf(up_lo(u.z), w[4], ep);
  ep = fmaf(up_hi(u.z), w[5], ep);
  ep = fmaf(up_lo(u.w), w[6], ep);
  ep = fmaf(up_hi(u.w), w[7], ep);
  return ep;
}

__global__ __launch_bounds__(256) void agg_csr(const int* __restrict__ eoff,
                                               const int* __restrict__ esrc,
                                               const unsigned* __restrict__ easb,
                                               const float* __restrict__ Wel,
                                               const float* __restrict__ attl,
                                               const unsigned* __restrict__ xlb,
                                               const unsigned* __restrict__ xrb,
                                               const float* __restrict__ cb,
                                               float* __restrict__ buf,
                                               float* __restrict__ ssum,
                                               float* __restrict__ ssq) {
  __shared__ float sA[256], sB[256], sC[256], sD[256];
  int t = threadIdx.x;
  int l = t & 63;
  int sub = t >> 6;
  int c0 = l * 2;
  float w0[8], w1[8];
#pragma unroll
  for (int k = 0; k < 8; k++) {
    float2 wv = *(const float2*)&Wel[k * H_ + c0];
    w0[k] = wv.x; w1[k] = wv.y;
  }
  float2 attv = *(const float2*)&attl[c0];
  float2 cbv = *(const float2*)&cb[c0];
  const uint4* eas4 = (const uint4*)easb;
  float a1_0 = 0.f, a1_1 = 0.f, a2_0 = 0.f, a2_1 = 0.f;
  for (int n = blockIdx.x * 4 + sub; n < N_; n += gridDim.x * 4) {
    unsigned xru = xrb[(size_t)n * 64 + l];
    float xr0 = up_lo(xru), xr1 = up_hi(xru);
    int e0 = eoff[n], e1 = eoff[n + 1];
    float acc0 = 0.f, acc1 = 0.f, den = 0.f;
    int j = e0;
    for (; j + 4 <= e1; j += 4) {
      int s0 = esrc[j], s1 = esrc[j + 1], s2 = esrc[j + 2], s3 = esrc[j + 3];
      uint4 u0 = eas4[j], u1 = eas4[j + 1], u2 = eas4[j + 2], u3 = eas4[j + 3];
      unsigned xu0 = xlb[(size_t)s0 * 64 + l];
      unsigned xu1 = xlb[(size_t)s1 * 64 + l];
      unsigned xu2 = xlb[(size_t)s2 * 64 + l];
      unsigned xu3 = xlb[(size_t)s3 * 64 + l];
      float x00 = up_lo(xu0), x01 = up_hi(xu0);
      float x10 = up_lo(xu1), x11 = up_hi(xu1);
      float x20 = up_lo(xu2), x21 = up_hi(xu2);
      float x30 = up_lo(xu3), x31 = up_hi(xu3);
      float m00 = x00 + xr0 + ep8u(u0, w0);
      float m01 = x01 + xr1 + ep8u(u0, w1);
      float m10 = x10 + xr0 + ep8u(u1, w0);
      float m11 = x11 + xr1 + ep8u(u1, w1);
      float m20 = x20 + xr0 + ep8u(u2, w0);
      float m21 = x21 + xr1 + ep8u(u2, w1);
      float m30 = x30 + xr0 + ep8u(u3, w0);
      float m31 = x31 + xr1 + ep8u(u3, w1);
      m00 = (m00 > 0.f) ? m00 : 0.2f * m00;
      m01 = (m01 > 0.f) ? m01 : 0.2f * m01;
      m10 = (m10 > 0.f) ? m10 : 0.2f * m10;
      m11 = (m11 > 0.f) ? m11 : 0.2f * m11;
      m20 = (m20 > 0.f) ? m20 : 0.2f * m20;
      m21 = (m21 > 0.f) ? m21 : 0.2f * m21;
      m30 = (m30 > 0.f) ? m30 : 0.2f * m30;
      m31 = (m31 > 0.f) ? m31 : 0.2f * m31;
      float p0 = fmaf(m00, attv.x, m01 * attv.y);
      float p1 = fmaf(m10, attv.x, m11 * attv.y);
      float p2 = fmaf(m20, attv.x, m21 * attv.y);
      float p3 = fmaf(m30, attv.x, m31 * attv.y);
#pragma unroll
      for (int off = 8; off > 0; off >>= 1) {
        p0 += __shfl_xor(p0, off, 64);
        p1 += __shfl_xor(p1, off, 64);
        p2 += __shfl_xor(p2, off, 64);
        p3 += __shfl_xor(p3, off, 64);
      }
      float e0v = __expf(p0), e1v = __expf(p1), e2v = __expf(p2), e3v = __expf(p3);
      acc0 = fmaf(e0v, x00, acc0); acc1 = fmaf(e0v, x01, acc1);
      acc0 = fmaf(e1v, x10, acc0); acc1 = fmaf(e1v, x11, acc1);
      acc0 = fmaf(e2v, x20, acc0); acc1 = fmaf(e2v, x21, acc1);
      acc0 = fmaf(e3v, x30, acc0); acc1 = fmaf(e3v, x31, acc1);
      den += (e0v + e1v) + (e2v + e3v);
    }
    for (; j < e1; j++) {
      int s0 = esrc[j];
      uint4 u0 = eas4[j];
      unsigned xu0 = xlb[(size_t)s0 * 64 + l];
      float x00 = up_lo(xu0), x01 = up_hi(xu0);
      float m00 = x00 + xr0 + ep8u(u0, w0);
      float m01 = x01 + xr1 + ep8u(u0, w1);
      m00 = (m00 > 0.f) ? m00 : 0.2f * m00;
      m01 = (m01 > 0.f) ? m01 : 0.2f * m01;
      float p0 = fmaf(m00, attv.x, m01 * attv.y);
#pragma unroll
      for (int off = 8; off > 0; off >>= 1) p0 += __shfl_xor(p0, off, 64);
      float e0v = __expf(p0);
      acc0 = fmaf(e0v, x00, acc0);
      acc1 = fmaf(e0v, x01, acc1);
      den += e0v;
    }
    float inv = 1.f / (den + 1e-16f);
    float h0 = acc0 * inv + cbv.x;
    float h1 = acc1 * inv + cbv.y;
    *(float2*)&buf[(size_t)n * H_ + c0] = make_float2(h0, h1);
    a1_0 += h0; a1_1 += h1;
    a2_0 = fmaf(h0, h0, a2_0); a2_1 = fmaf(h1, h1, a2_1);
  }
  sA[t] = a1_0; sB[t] = a1_1; sC[t] = a2_0; sD[t] = a2_1;
  __syncthreads();
  if (t < 64) {
    float r1 = sA[t] + sA[t + 64] + sA[t + 128] + sA[t + 192];
    float r2 = sB[t] + sB[t + 64] + sB[t + 128] + sB[t + 192];
    float r3 = sC[t] + sC[t + 64] + sC[t + 128] + sC[t + 192];
    float r4 = sD[t] + sD[t + 64] + sD[t + 128] + sD[t + 192];
    atomicAdd(&ssum[2 * t], r1);
    atomicAdd(&ssum[2 * t + 1], r2);
    atomicAdd(&ssq[2 * t], r3);
    atomicAdd(&ssq[2 * t + 1], r4);
  }
}

// ---------------- BN apply with inline finalize ----------------
__global__ __launch_bounds__(256) void apply_bn_relu(const float* __restrict__ y,
                                                     float* __restrict__ out,
                                                     const float* __restrict__ g,
                                                     const float* __restrict__ beta,
                                                     const float* __restrict__ ssum,
                                                     const float* __restrict__ ssq,
                                                     float rows_inv,
                                                     long total, int cmask) {
  long i = (long)blockIdx.x * 256 + threadIdx.x;
  if (i >= total) return;
  int c = (int)i & cmask;
  float m = ssum[c] * rows_inv;
  float rs = rsqrtf(ssq[c] * rows_inv - m * m + 1e-5f);
  float v = g[c] * (y[i] - m) * rs + beta[c];
  out[i] = fmaxf(v, 0.f);
}

// ---------------- pooling with fused layer-2 residual (inline BN finalize) ----
__global__ __launch_bounds__(128) void pool_residual(const int* __restrict__ goff,
                                                     const float* __restrict__ xn,
                                                     const float* __restrict__ buf,
                                                     const float* __restrict__ g,
                                                     const float* __restrict__ beta,
                                                     const float* __restrict__ ssum,
                                                     const float* __restrict__ ssq,
                                                     float rows_inv,
                                                     float* __restrict__ xg) {
  int gr = blockIdx.x;
  int t = threadIdx.x;
  int n0 = goff[gr], n1 = goff[gr + 1];
  float mm = ssum[t] * rows_inv;
  float rr = rsqrtf(ssq[t] * rows_inv - mm * mm + 1e-5f);
  float gg = g[t], bb = beta[t];
  float s = 0.f, mx = -INFINITY;
  for (int n = n0; n < n1; n++) {
    float w = gg * (buf[(size_t)n * H_ + t] - mm) * rr + bb;
    w = (w > 0.f) ? w : (__expf(w) - 1.f);
    float v = xn[(size_t)n * H_ + t] + w;
    s += v;
    mx = fmaxf(mx, v);
  }
  float c = (float)(n1 - n0);
  xg[gr * 384 + t] = s / fmaxf(c, 1.f);
  xg[gr * 384 + 128 + t] = (c > 0.f) ? mx : 0.f;
  xg[gr * 384 + 256 + t] = s;
}

// ---------------- MLP GEMMs (fused colstats) ----------------
template <int K, int COLS>
__global__ void mlp_gemm(const float* __restrict__ A, const float* __restrict__ W,
                         const float* __restrict__ b, float* __restrict__ Y, int rows,
                         float* __restrict__ ssum, float* __restrict__ ssq) {
  __shared__ float xs[8][K];
  int t = threadIdx.x;
  int row0 = blockIdx.x * 8;
  for (int i = t; i < 8 * K; i += COLS) {
    int r = i / K, k = i % K;
    int row = row0 + r;
    xs[r][k] = (row < rows) ? A[row * K + k] : 0.f;
  }
  __syncthreads();
  float acc[8];
#pragma unroll
  for (int r = 0; r < 8; r++) acc[r] = 0.f;
  for (int k = 0; k < K; k++) {
    float w = W[k * COLS + t];
#pragma unroll
    for (int r = 0; r < 8; r++) acc[r] = fmaf(xs[r][k], w, acc[r]);
  }
  float bb = b[t];
  float a1 = 0.f, a2 = 0.f;
#pragma unroll
  for (int r = 0; r < 8; r++) {
    int row = row0 + r;
    if (row < rows) {
      float v = acc[r] + bb;
      Y[row * COLS + t] = v;
      a1 += v;
      a2 = fmaf(v, v, a2);
    }
  }
  atomicAdd(&ssum[t], a1);
  atomicAdd(&ssq[t], a2);
}

// ---------------- head ----------------
__global__ __launch_bounds__(64) void head_kernel(const float* __restrict__ u,
                                                  const float* __restrict__ W,
                                                  const float* __restrict__ b,
                                                  float* __restrict__ out) {
  __shared__ float row[128];
  int g = blockIdx.x;
  int t = threadIdx.x;
  row[t] = u[g * 128 + t];
  row[t + 64] = u[g * 128 + 64 + t];
  __syncthreads();
  if (t < 12) {
    float acc = b[t];
    for (int k = 0; k < 128; k++) acc = fmaf(row[k], W[k * 12 + t], acc);
    out[g * 12 + t] = 1.f / (1.f + expf(-acc));
  }
}

// ---------------- launcher ----------------
extern "C" void kernel_launch(void* const* d_in, const int* in_sizes, int n_in, void* d_out,
                              int out_size, void* d_ws, size_t ws_size, hipStream_t stream) {
  (void)in_sizes; (void)n_in; (void)out_size; (void)ws_size;
  const float* x       = (const float*)d_in[0];
  const int*   ei      = (const int*)d_in[1];
  const float* ea      = (const float*)d_in[2];
  const int*   batch   = (const int*)d_in[3];
  const float* in_W    = (const float*)d_in[4];
  const float* in_b    = (const float*)d_in[5];
  const float* in_g    = (const float*)d_in[6];
  const float* in_beta = (const float*)d_in[7];
  const float* Wl      = (const float*)d_in[8];
  const float* Wr      = (const float*)d_in[9];
  const float* We      = (const float*)d_in[10];
  const float* att     = (const float*)d_in[11];
  const float* conv_b  = (const float*)d_in[12];
  const float* bn_g    = (const float*)d_in[13];
  const float* bn_b    = (const float*)d_in[14];
  const float* t1_W    = (const float*)d_in[15];
  const float* t1_b    = (const float*)d_in[16];
  const float* t1_g    = (const float*)d_in[17];
  const float* t1_beta = (const float*)d_in[18];
  const float* t2_W    = (const float*)d_in[19];
  const float* t2_b    = (const float*)d_in[20];
  const float* t2_g    = (const float*)d_in[21];
  const float* t2_beta = (const float*)d_in[22];
  const float* head_W  = (const float*)d_in[23];
  const float* head_b  = (const float*)d_in[24];
  float* out = (float*)d_out;

  float* p = (float*)d_ws;
  float* xn    = p; p += N_ * H_;
  float* buf   = p; p += N_ * H_;
  float* sstat = p; p += 6 * 512;   // 6 stages x (ssum 256 | ssq 256)
  float* xg    = p; p += G_ * 384;
  float* u1    = p; p += G_ * 256;
  float* u2    = p; p += G_ * 128;
  unsigned* up = (unsigned*)p;
  unsigned* xlb  = up; up += (size_t)N_ * 64;
  unsigned* xrb  = up; up += (size_t)N_ * 64;
  unsigned* easb = up; up += (size_t)E_ * 4;
  unsigned short* wpack = (unsigned short*)up; up += 3 * 32768 / 2;
  int* ip = (int*)up;
  int* deg    = ip; ip += N_;
  int* eoff   = ip; ip += N_ + 1;
  int* cursor = ip; ip += N_;
  int* goff   = ip; ip += G_ + 1;
  int* esrc   = ip; ip += E_;
  int* bsum   = ip; ip += 64;
  int* boff   = ip; ip += 64;

#define SSUM(s) (sstat + (s) * 512)
#define SSQ(s)  (sstat + (s) * 512 + 256)

  // ---- build CSR structures + pre-pack weights ----
  hipMemsetAsync(deg, 0, (size_t)N_ * sizeof(int), stream);
  hipMemsetAsync(sstat, 0, 6 * 512 * sizeof(float), stream);
  hist_kernel<<<1024, 256, 0, stream>>>(ei + E_, E_, deg);
  scan_local<<<49, 1024, 0, stream>>>(deg, eoff, bsum, N_);
  scan_bsum<<<1, 64, 0, stream>>>(bsum, boff, 49);
  scan_add<<<49, 1024, 0, stream>>>(eoff, boff, cursor, N_);
  edge_scatter<<<(E_ + 255) / 256, 256, 0, stream>>>(ei, ea, cursor, esrc, easb);
  goff_from_sorted<<<(N_ + 255) / 256, 256, 0, stream>>>(batch, goff);
  pack_weights<<<384, 256, 0, stream>>>(Wl, Wr, wpack);

  // ---- input layer (stats -> stage 0) ----
  in_gemm<<<(N_ + 31) / 32, 256, 0, stream>>>(x, in_W, in_b, buf, SSUM(0), SSQ(0));

  // ---- 3 GATv2 layers ----
  const float rnInv = 1.f / N_;
  const int GT = (N_ + 63) / 64;  // 782
  gemm_mfma<1><<<GT, 256, 0, stream>>>(xn, buf, in_g, in_beta, SSUM(0), SSQ(0), rnInv,
                                       wpack, xlb, xrb);
  agg_csr<<<2048, 256, 0, stream>>>(eoff, esrc, easb, We, att, xlb, xrb, conv_b,
                                    buf, SSUM(1), SSQ(1));
  gemm_mfma<2><<<GT, 256, 0, stream>>>(xn, buf, bn_g, bn_b, SSUM(1), SSQ(1), rnInv,
                                       wpack + 32768, xlb, xrb);
  agg_csr<<<2048, 256, 0, stream>>>(eoff, esrc, easb, We + 8 * H_, att + H_, xlb, xrb,
                                    conv_b + H_, buf, SSUM(2), SSQ(2));
  gemm_mfma<2><<<GT, 256, 0, stream>>>(xn, buf, bn_g + H_, bn_b + H_, SSUM(2), SSQ(2),
                                       rnInv, wpack + 65536, xlb, xrb);
  agg_csr<<<2048, 256, 0, stream>>>(eoff, esrc, easb, We + 16 * H_, att + 2 * H_, xlb, xrb,
                                    conv_b + 2 * H_, buf, SSUM(3), SSQ(3));

  // ---- pooling with fused layer-2 residual (stage 3 stats) ----
  pool_residual<<<G_, 128, 0, stream>>>(goff, xn, buf, bn_g + 2 * H_, bn_b + 2 * H_,
                                        SSUM(3), SSQ(3), rnInv, xg);

  // ---- t1 (stats -> stage 4) ----
  const float rgInv = 1.f / G_;
  mlp_gemm<384, 256><<<G_ / 8, 256, 0, stream>>>(xg, t1_W, t1_b, u1, G_, SSUM(4), SSQ(4));
  apply_bn_relu<<<(G_ * 256 + 255) / 256, 256, 0, stream>>>(u1, u1, t1_g, t1_beta,
                                                            SSUM(4), SSQ(4), rgInv,
                                                            (long)G_ * 256, 255);

  // ---- t2 (stats -> stage 5) ----
  mlp_gemm<256, 128><<<G_ / 8, 128, 0, stream>>>(u1, t2_W, t2_b, u2, G_, SSUM(5), SSQ(5));
  apply_bn_relu<<<(G_ * 128 + 255) / 256, 256, 0, stream>>>(u2, u2, t2_g, t2_beta,
                                                            SSUM(5), SSQ(5), rgInv,
                                                            (long)G_ * 128, 127);

  // ---- head ----
  head_kernel<<<G_, 64, 0, stream>>>(u2, head_W, head_b, out);
#undef SSUM
#undef SSQ
}

// Round 12
// 866.841 us; speedup vs baseline: 1.0918x; 1.0612x over previous
//
#include <hip/hip_runtime.h>
#include <math.h>

// ToxicityGATv2 — round 12: EXACT round-9 structure (best so far, 847 µs) with
// ONE change: gemm_mfma epilogue replaced by the shfl-pair pack (verified in
// r10/r11) — removes 8x LDS-transpose rounds with full lgkmcnt(0) drains.

constexpr int N_ = 50000;
constexpr int E_ = 400000;
constexpr int G_ = 2000;
constexpr int H_ = 128;
constexpr int IN_ = 39;

typedef __attribute__((ext_vector_type(8))) short bf16x8;
typedef __attribute__((ext_vector_type(4))) float f32x4;

// ---------------- bf16 pack/unpack (RNE) ----------------
__device__ __forceinline__ unsigned pk_bf16(float a, float b) {
  unsigned ua = __float_as_uint(a);
  unsigned ub = __float_as_uint(b);
  ua = (ua + 0x7fffu + ((ua >> 16) & 1u)) >> 16;
  ub = (ub + 0x7fffu + ((ub >> 16) & 1u)) & 0xffff0000u;
  return ua | ub;
}
__device__ __forceinline__ unsigned short bf16_1(float x) {
  unsigned u = __float_as_uint(x);
  u = (u + 0x7fffu + ((u >> 16) & 1u)) >> 16;
  return (unsigned short)u;
}
__device__ __forceinline__ float up_lo(unsigned u) { return __uint_as_float(u << 16); }
__device__ __forceinline__ float up_hi(unsigned u) { return __uint_as_float(u & 0xffff0000u); }

// ---------------- histogram ----------------
__global__ __launch_bounds__(256) void hist_kernel(const int* __restrict__ keys, int n,
                                                   int* __restrict__ cnt) {
  for (int i = blockIdx.x * 256 + threadIdx.x; i < n; i += gridDim.x * 256)
    atomicAdd(&cnt[keys[i]], 1);
}

// ---------------- multi-block scan ----------------
__global__ __launch_bounds__(1024) void scan_local(const int* __restrict__ in,
                                                   int* __restrict__ outx,
                                                   int* __restrict__ bsum, int n) {
  __shared__ int wsum[16];
  int t = threadIdx.x, lane = t & 63, wid = t >> 6;
  int idx = blockIdx.x * 1024 + t;
  int v = (idx < n) ? in[idx] : 0;
  int x = v;
#pragma unroll
  for (int off = 1; off < 64; off <<= 1) {
    int y = __shfl_up(x, off, 64);
    if (lane >= off) x += y;
  }
  if (lane == 63) wsum[wid] = x;
  __syncthreads();
  if (t == 0) {
    int acc = 0;
#pragma unroll
    for (int w = 0; w < 16; w++) { int tmp = wsum[w]; wsum[w] = acc; acc += tmp; }
    bsum[blockIdx.x] = acc;
  }
  __syncthreads();
  if (idx < n) outx[idx] = wsum[wid] + x - v;
}

__global__ __launch_bounds__(64) void scan_bsum(const int* __restrict__ bsum,
                                                int* __restrict__ boff, int nb) {
  int t = threadIdx.x;
  int v = (t < nb) ? bsum[t] : 0;
  int x = v;
#pragma unroll
  for (int off = 1; off < 64; off <<= 1) {
    int y = __shfl_up(x, off, 64);
    if (t >= off) x += y;
  }
  boff[t] = x - v;
}

__global__ __launch_bounds__(1024) void scan_add(int* __restrict__ eoff,
                                                 const int* __restrict__ boff,
                                                 int* __restrict__ cursor, int n) {
  int idx = blockIdx.x * 1024 + threadIdx.x;
  if (idx < n) {
    int e = eoff[idx] + boff[idx >> 10];
    eoff[idx] = e;
    cursor[idx] = e;
  }
  if (idx == 0) eoff[n] = E_;
}

// ---------------- goff from sorted batch ----------------
__global__ __launch_bounds__(256) void goff_from_sorted(const int* __restrict__ batch,
                                                        int* __restrict__ goff) {
  int i = blockIdx.x * 256 + threadIdx.x;
  if (i >= N_) return;
  int bi = batch[i];
  int bp = (i == 0) ? -1 : batch[i - 1];
  for (int g = bp + 1; g <= bi; g++) goff[g] = i;
  if (i == N_ - 1) {
    for (int g = bi + 1; g <= G_; g++) goff[g] = N_;
  }
}

// ---------------- edge scatter (bf16 attrs) ----------------
__global__ __launch_bounds__(256) void edge_scatter(const int* __restrict__ ei,
                                                    const float* __restrict__ ea,
                                                    int* __restrict__ cursor,
                                                    int* __restrict__ esrc,
                                                    unsigned* __restrict__ easb) {
  int e = blockIdx.x * 256 + threadIdx.x;
  if (e >= E_) return;
  int src = ei[e];
  int dst = ei[E_ + e];
  int j = atomicAdd(&cursor[dst], 1);
  esrc[j] = src;
  const float4* eav = (const float4*)(ea + (size_t)e * 8);
  float4 a0 = eav[0], a1 = eav[1];
  uint4 o;
  o.x = pk_bf16(a0.x, a0.y);
  o.y = pk_bf16(a0.z, a0.w);
  o.z = pk_bf16(a1.x, a1.y);
  o.w = pk_bf16(a1.z, a1.w);
  ((uint4*)easb)[j] = o;
}

// ---------------- weight pre-pack: wpack[l][n][k] = bf16([Wl|Wr][k][n]) -------
__global__ __launch_bounds__(256) void pack_weights(const float* __restrict__ Wl,
                                                    const float* __restrict__ Wr,
                                                    unsigned short* __restrict__ wpack) {
  int i = blockIdx.x * 256 + threadIdx.x;
  if (i >= 3 * 128 * 256) return;
  int l = i >> 15;
  int rem = i & 32767;
  int k = rem >> 8;
  int n = rem & 255;
  const float* Wsrc = (n < 128) ? (Wl + l * H_ * H_) : (Wr + l * H_ * H_);
  int nn = n & 127;
  wpack[(size_t)l * 32768 + n * 128 + k] = bf16_1(Wsrc[k * H_ + nn]);
}

// ---------------- input GEMM + fused colstats ----------------
__global__ __launch_bounds__(256) void in_gemm(const float* __restrict__ x,
                                               const float* __restrict__ W,
                                               const float* __restrict__ b,
                                               float* __restrict__ y,
                                               float* __restrict__ ssum,
                                               float* __restrict__ ssq) {
  __shared__ float xs[32][40];
  __shared__ float s1[256], s2[256];
  int t = threadIdx.x;
  int row0 = blockIdx.x * 32;
  for (int i = t; i < 32 * IN_; i += 256) {
    int r = i / IN_, k = i % IN_;
    int row = row0 + r;
    xs[r][k] = (row < N_) ? x[row * IN_ + k] : 0.f;
  }
  __syncthreads();
  int col = t & 127;
  int half = t >> 7;
  float acc[16];
#pragma unroll
  for (int r = 0; r < 16; r++) acc[r] = 0.f;
  for (int k = 0; k < IN_; k++) {
    float w = W[k * H_ + col];
#pragma unroll
    for (int r = 0; r < 16; r++) acc[r] = fmaf(xs[half * 16 + r][k], w, acc[r]);
  }
  float bb = b[col];
  float a1 = 0.f, a2 = 0.f;
#pragma unroll
  for (int r = 0; r < 16; r++) {
    int row = row0 + half * 16 + r;
    float v = acc[r] + bb;
    if (row < N_) {
      y[row * H_ + col] = v;
      a1 += v;
      a2 = fmaf(v, v, a2);
    }
  }
  s1[t] = a1; s2[t] = a2;
  __syncthreads();
  if (t < 128) {
    atomicAdd(&ssum[t], s1[t] + s1[t + 128]);
    atomicAdd(&ssq[t], s2[t] + s2[t + 128]);
  }
}

// ---------------- MFMA node GEMM (r9 body + shfl-pair epilogue) ----------
// MODE 1: v=relu(bn(buf)); xn=v.  MODE 2: v=xn+elu(bn(buf)); xn=v.
template <int MODE>
__global__ __launch_bounds__(256) void gemm_mfma(float* __restrict__ xn,
                                                 const float* __restrict__ buf,
                                                 const float* __restrict__ g,
                                                 const float* __restrict__ beta,
                                                 const float* __restrict__ ssum,
                                                 const float* __restrict__ ssq,
                                                 float rows_inv,
                                                 const unsigned short* __restrict__ wp,
                                                 unsigned* __restrict__ xlb,
                                                 unsigned* __restrict__ xrb) {
  __shared__ short a_s[64][136];  // 17408 B: 64 rows x 128 k
  __shared__ short b_s[256][40];  // 20480 B: 256 n x 32 k chunk
  int t = threadIdx.x;
  int lane = t & 63, w = t >> 6;
  int quad = lane >> 4, lc = lane & 15;
  int row0 = blockIdx.x * 64;

  // ---- stage A (fused BN epilogue, fp32 xn updated, bf16 into LDS) ----
  {
    int r = t >> 2;
    int row = row0 + r;
    int kb0 = (t & 3) * 32;
    bool valid = row < N_;
    for (int kk = 0; kk < 32; kk += 4) {
      int c = kb0 + kk;
      float4 v = make_float4(0.f, 0.f, 0.f, 0.f);
      if (valid) {
        float4 bv = *(const float4*)&buf[(size_t)row * H_ + c];
        float4 gv = *(const float4*)&g[c];
        float4 be = *(const float4*)&beta[c];
        float4 s1 = *(const float4*)&ssum[c];
        float4 s2 = *(const float4*)&ssq[c];
        float m0 = s1.x * rows_inv, m1 = s1.y * rows_inv;
        float m2 = s1.z * rows_inv, m3 = s1.w * rows_inv;
        float r0 = rsqrtf(s2.x * rows_inv - m0 * m0 + 1e-5f);
        float r1 = rsqrtf(s2.y * rows_inv - m1 * m1 + 1e-5f);
        float r2 = rsqrtf(s2.z * rows_inv - m2 * m2 + 1e-5f);
        float r3 = rsqrtf(s2.w * rows_inv - m3 * m3 + 1e-5f);
        float t0 = gv.x * (bv.x - m0) * r0 + be.x;
        float t1 = gv.y * (bv.y - m1) * r1 + be.y;
        float t2 = gv.z * (bv.z - m2) * r2 + be.z;
        float t3 = gv.w * (bv.w - m3) * r3 + be.w;
        if (MODE == 1) {
          v = make_float4(fmaxf(t0, 0.f), fmaxf(t1, 0.f), fmaxf(t2, 0.f), fmaxf(t3, 0.f));
        } else {
          float4 xo = *(const float4*)&xn[(size_t)row * H_ + c];
          v.x = xo.x + ((t0 > 0.f) ? t0 : (__expf(t0) - 1.f));
          v.y = xo.y + ((t1 > 0.f) ? t1 : (__expf(t1) - 1.f));
          v.z = xo.z + ((t2 > 0.f) ? t2 : (__expf(t2) - 1.f));
          v.w = xo.w + ((t3 > 0.f) ? t3 : (__expf(t3) - 1.f));
        }
        *(float4*)&xn[(size_t)row * H_ + c] = v;
      }
      uint2 pk;
      pk.x = pk_bf16(v.x, v.y);
      pk.y = pk_bf16(v.z, v.w);
      *(uint2*)&a_s[r][c] = pk;
    }
  }

  f32x4 acc[16];
#pragma unroll
  for (int nt = 0; nt < 16; nt++) acc[nt] = (f32x4){0.f, 0.f, 0.f, 0.f};

  for (int kb = 0; kb < 4; kb++) {
    __syncthreads();
    // stage B chunk: vectorized copy from pre-packed weights (16 KB)
    for (int i = t; i < 1024; i += 256) {
      int n = i >> 2;
      int k8 = (i & 3) * 8;
      *(uint4*)&b_s[n][k8] = *(const uint4*)&wp[(size_t)n * 128 + kb * 32 + k8];
    }
    __syncthreads();
    bf16x8 av = *(const bf16x8*)&a_s[w * 16 + lc][kb * 32 + quad * 8];
#pragma unroll
    for (int nt = 0; nt < 16; nt++) {
      bf16x8 bv = *(const bf16x8*)&b_s[nt * 16 + lc][quad * 8];
      acc[nt] = __builtin_amdgcn_mfma_f32_16x16x32_bf16(av, bv, acc[nt], 0, 0, 0);
    }
  }

  // ---- epilogue: shfl-pair pack, direct stores (no LDS, no drains) ----
  int rowg0 = row0 + w * 16 + quad * 4;
#pragma unroll
  for (int nt = 0; nt < 16; nt++) {
    unsigned* xout = (nt < 8) ? xlb : xrb;
    int cp0 = (nt & 7) * 8;
#pragma unroll
    for (int rr = 0; rr < 4; rr++) {
      float v = acc[nt][rr];
      float pv = __shfl_xor(v, 1, 64);
      int rowg = rowg0 + rr;
      if (!(lc & 1) && rowg < N_) {
        unsigned u = pk_bf16(v, pv);
        xout[(size_t)rowg * 64 + cp0 + (lc >> 1)] = u;
      }
    }
  }
}

// ---------------- CSR aggregation (round-5 proven body) ----------------
__device__ __forceinline__ float ep8u(const uint4& u, const float* w) {
  float ep = up_lo(u.x) * w[0];
  ep = fmaf(up_hi(u.x), w[1], ep);
  ep = fmaf(up_lo(u.y), w[2], ep);
  ep = fmaf(up_hi(u.y), w[3], ep);
  ep = fmaf(up_lo(u.z), w[4], ep);
  ep = fmaf(up_hi(u.z), w[5], ep);
  ep = fmaf(up_lo(u.w), w[6], ep);
  ep = fmaf(up_hi(u.w), w[7], ep);
  return ep;
}

__global__ __launch_bounds__(256) void agg_csr(const int* __restrict__ eoff,
                                               const int* __restrict__ esrc,
                                               const unsigned* __restrict__ easb,
                                               const float* __restrict__ Wel,
                                               const float* __restrict__ attl,
                                               const unsigned* __restrict__ xlb,
                                               const unsigned* __restrict__ xrb,
                                               const float* __restrict__ cb,
                                               float* __restrict__ buf,
                                               float* __restrict__ ssum,
                                               float* __restrict__ ssq) {
  __shared__ float sA[256], sB[256], sC[256], sD[256];
  int t = threadIdx.x;
  int l = t & 63;
  int sub = t >> 6;
  int c0 = l * 2;
  float w0[8], w1[8];
#pragma unroll
  for (int k = 0; k < 8; k++) {
    float2 wv = *(const float2*)&Wel[k * H_ + c0];
    w0[k] = wv.x; w1[k] = wv.y;
  }
  float2 attv = *(const float2*)&attl[c0];
  float2 cbv = *(const float2*)&cb[c0];
  const uint4* eas4 = (const uint4*)easb;
  float a1_0 = 0.f, a1_1 = 0.f, a2_0 = 0.f, a2_1 = 0.f;
  for (int n = blockIdx.x * 4 + sub; n < N_; n += gridDim.x * 4) {
    unsigned xru = xrb[(size_t)n * 64 + l];
    float xr0 = up_lo(xru), xr1 = up_hi(xru);
    int e0 = eoff[n], e1 = eoff[n + 1];
    float acc0 = 0.f, acc1 = 0.f, den = 0.f;
    int j = e0;
    for (; j + 4 <= e1; j += 4) {
      int s0 = esrc[j], s1 = esrc[j + 1], s2 = esrc[j + 2], s3 = esrc[j + 3];
      uint4 u0 = eas4[j], u1 = eas4[j + 1], u2 = eas4[j + 2], u3 = eas4[j + 3];
      unsigned xu0 = xlb[(size_t)s0 * 64 + l];
      unsigned xu1 = xlb[(size_t)s1 * 64 + l];
      unsigned xu2 = xlb[(size_t)s2 * 64 + l];
      unsigned xu3 = xlb[(size_t)s3 * 64 + l];
      float x00 = up_lo(xu0), x01 = up_hi(xu0);
      float x10 = up_lo(xu1), x11 = up_hi(xu1);
      float x20 = up_lo(xu2), x21 = up_hi(xu2);
      float x30 = up_lo(xu3), x31 = up_hi(xu3);
      float m00 = x00 + xr0 + ep8u(u0, w0);
      float m01 = x01 + xr1 + ep8u(u0, w1);
      float m10 = x10 + xr0 + ep8u(u1, w0);
      float m11 = x11 + xr1 + ep8u(u1, w1);
      float m20 = x20 + xr0 + ep8u(u2, w0);
      float m21 = x21 + xr1 + ep8u(u2, w1);
      float m30 = x30 + xr0 + ep8u(u3, w0);
      float m31 = x31 + xr1 + ep8u(u3, w1);
      m00 = (m00 > 0.f) ? m00 : 0.2f * m00;
      m01 = (m01 > 0.f) ? m01 : 0.2f * m01;
      m10 = (m10 > 0.f) ? m10 : 0.2f * m10;
      m11 = (m11 > 0.f) ? m11 : 0.2f * m11;
      m20 = (m20 > 0.f) ? m20 : 0.2f * m20;
      m21 = (m21 > 0.f) ? m21 : 0.2f * m21;
      m30 = (m30 > 0.f) ? m30 : 0.2f * m30;
      m31 = (m31 > 0.f) ? m31 : 0.2f * m31;
      float p0 = fmaf(m00, attv.x, m01 * attv.y);
      float p1 = fmaf(m10, attv.x, m11 * attv.y);
      float p2 = fmaf(m20, attv.x, m21 * attv.y);
      float p3 = fmaf(m30, attv.x, m31 * attv.y);
#pragma unroll
      for (int off = 8; off > 0; off >>= 1) {
        p0 += __shfl_xor(p0, off, 64);
        p1 += __shfl_xor(p1, off, 64);
        p2 += __shfl_xor(p2, off, 64);
        p3 += __shfl_xor(p3, off, 64);
      }
      float e0v = __expf(p0), e1v = __expf(p1), e2v = __expf(p2), e3v = __expf(p3);
      acc0 = fmaf(e0v, x00, acc0); acc1 = fmaf(e0v, x01, acc1);
      acc0 = fmaf(e1v, x10, acc0); acc1 = fmaf(e1v, x11, acc1);
      acc0 = fmaf(e2v, x20, acc0); acc1 = fmaf(e2v, x21, acc1);
      acc0 = fmaf(e3v, x30, acc0); acc1 = fmaf(e3v, x31, acc1);
      den += (e0v + e1v) + (e2v + e3v);
    }
    for (; j < e1; j++) {
      int s0 = esrc[j];
      uint4 u0 = eas4[j];
      unsigned xu0 = xlb[(size_t)s0 * 64 + l];
      float x00 = up_lo(xu0), x01 = up_hi(xu0);
      float m00 = x00 + xr0 + ep8u(u0, w0);
      float m01 = x01 + xr1 + ep8u(u0, w1);
      m00 = (m00 > 0.f) ? m00 : 0.2f * m00;
      m01 = (m01 > 0.f) ? m01 : 0.2f * m01;
      float p0 = fmaf(m00, attv.x, m01 * attv.y);
#pragma unroll
      for (int off = 8; off > 0; off >>= 1) p0 += __shfl_xor(p0, off, 64);
      float e0v = __expf(p0);
      acc0 = fmaf(e0v, x00, acc0);
      acc1 = fmaf(e0v, x01, acc1);
      den += e0v;
    }
    float inv = 1.f / (den + 1e-16f);
    float h0 = acc0 * inv + cbv.x;
    float h1 = acc1 * inv + cbv.y;
    *(float2*)&buf[(size_t)n * H_ + c0] = make_float2(h0, h1);
    a1_0 += h0; a1_1 += h1;
    a2_0 = fmaf(h0, h0, a2_0); a2_1 = fmaf(h1, h1, a2_1);
  }
  sA[t] = a1_0; sB[t] = a1_1; sC[t] = a2_0; sD[t] = a2_1;
  __syncthreads();
  if (t < 64) {
    float r1 = sA[t] + sA[t + 64] + sA[t + 128] + sA[t + 192];
    float r2 = sB[t] + sB[t + 64] + sB[t + 128] + sB[t + 192];
    float r3 = sC[t] + sC[t + 64] + sC[t + 128] + sC[t + 192];
    float r4 = sD[t] + sD[t + 64] + sD[t + 128] + sD[t + 192];
    atomicAdd(&ssum[2 * t], r1);
    atomicAdd(&ssum[2 * t + 1], r2);
    atomicAdd(&ssq[2 * t], r3);
    atomicAdd(&ssq[2 * t + 1], r4);
  }
}

// ---------------- BN apply with inline finalize ----------------
__global__ __launch_bounds__(256) void apply_bn_relu(const float* __restrict__ y,
                                                     float* __restrict__ out,
                                                     const float* __restrict__ g,
                                                     const float* __restrict__ beta,
                                                     const float* __restrict__ ssum,
                                                     const float* __restrict__ ssq,
                                                     float rows_inv,
                                                     long total, int cmask) {
  long i = (long)blockIdx.x * 256 + threadIdx.x;
  if (i >= total) return;
  int c = (int)i & cmask;
  float m = ssum[c] * rows_inv;
  float rs = rsqrtf(ssq[c] * rows_inv - m * m + 1e-5f);
  float v = g[c] * (y[i] - m) * rs + beta[c];
  out[i] = fmaxf(v, 0.f);
}

// ---------------- pooling with fused layer-2 residual (inline BN finalize) ----
__global__ __launch_bounds__(128) void pool_residual(const int* __restrict__ goff,
                                                     const float* __restrict__ xn,
                                                     const float* __restrict__ buf,
                                                     const float* __restrict__ g,
                                                     const float* __restrict__ beta,
                                                     const float* __restrict__ ssum,
                                                     const float* __restrict__ ssq,
                                                     float rows_inv,
                                                     float* __restrict__ xg) {
  int gr = blockIdx.x;
  int t = threadIdx.x;
  int n0 = goff[gr], n1 = goff[gr + 1];
  float mm = ssum[t] * rows_inv;
  float rr = rsqrtf(ssq[t] * rows_inv - mm * mm + 1e-5f);
  float gg = g[t], bb = beta[t];
  float s = 0.f, mx = -INFINITY;
  for (int n = n0; n < n1; n++) {
    float w = gg * (buf[(size_t)n * H_ + t] - mm) * rr + bb;
    w = (w > 0.f) ? w : (__expf(w) - 1.f);
    float v = xn[(size_t)n * H_ + t] + w;
    s += v;
    mx = fmaxf(mx, v);
  }
  float c = (float)(n1 - n0);
  xg[gr * 384 + t] = s / fmaxf(c, 1.f);
  xg[gr * 384 + 128 + t] = (c > 0.f) ? mx : 0.f;
  xg[gr * 384 + 256 + t] = s;
}

// ---------------- MLP GEMMs (fused colstats) ----------------
template <int K, int COLS>
__global__ void mlp_gemm(const float* __restrict__ A, const float* __restrict__ W,
                         const float* __restrict__ b, float* __restrict__ Y, int rows,
                         float* __restrict__ ssum, float* __restrict__ ssq) {
  __shared__ float xs[8][K];
  int t = threadIdx.x;
  int row0 = blockIdx.x * 8;
  for (int i = t; i < 8 * K; i += COLS) {
    int r = i / K, k = i % K;
    int row = row0 + r;
    xs[r][k] = (row < rows) ? A[row * K + k] : 0.f;
  }
  __syncthreads();
  float acc[8];
#pragma unroll
  for (int r = 0; r < 8; r++) acc[r] = 0.f;
  for (int k = 0; k < K; k++) {
    float w = W[k * COLS + t];
#pragma unroll
    for (int r = 0; r < 8; r++) acc[r] = fmaf(xs[r][k], w, acc[r]);
  }
  float bb = b[t];
  float a1 = 0.f, a2 = 0.f;
#pragma unroll
  for (int r = 0; r < 8; r++) {
    int row = row0 + r;
    if (row < rows) {
      float v = acc[r] + bb;
      Y[row * COLS + t] = v;
      a1 += v;
      a2 = fmaf(v, v, a2);
    }
  }
  atomicAdd(&ssum[t], a1);
  atomicAdd(&ssq[t], a2);
}

// ---------------- head ----------------
__global__ __launch_bounds__(64) void head_kernel(const float* __restrict__ u,
                                                  const float* __restrict__ W,
                                                  const float* __restrict__ b,
                                                  float* __restrict__ out) {
  __shared__ float row[128];
  int g = blockIdx.x;
  int t = threadIdx.x;
  row[t] = u[g * 128 + t];
  row[t + 64] = u[g * 128 + 64 + t];
  __syncthreads();
  if (t < 12) {
    float acc = b[t];
    for (int k = 0; k < 128; k++) acc = fmaf(row[k], W[k * 12 + t], acc);
    out[g * 12 + t] = 1.f / (1.f + expf(-acc));
  }
}

// ---------------- launcher ----------------
extern "C" void kernel_launch(void* const* d_in, const int* in_sizes, int n_in, void* d_out,
                              int out_size, void* d_ws, size_t ws_size, hipStream_t stream) {
  (void)in_sizes; (void)n_in; (void)out_size; (void)ws_size;
  const float* x       = (const float*)d_in[0];
  const int*   ei      = (const int*)d_in[1];
  const float* ea      = (const float*)d_in[2];
  const int*   batch   = (const int*)d_in[3];
  const float* in_W    = (const float*)d_in[4];
  const float* in_b    = (const float*)d_in[5];
  const float* in_g    = (const float*)d_in[6];
  const float* in_beta = (const float*)d_in[7];
  const float* Wl      = (const float*)d_in[8];
  const float* Wr      = (const float*)d_in[9];
  const float* We      = (const float*)d_in[10];
  const float* att     = (const float*)d_in[11];
  const float* conv_b  = (const float*)d_in[12];
  const float* bn_g    = (const float*)d_in[13];
  const float* bn_b    = (const float*)d_in[14];
  const float* t1_W    = (const float*)d_in[15];
  const float* t1_b    = (const float*)d_in[16];
  const float* t1_g    = (const float*)d_in[17];
  const float* t1_beta = (const float*)d_in[18];
  const float* t2_W    = (const float*)d_in[19];
  const float* t2_b    = (const float*)d_in[20];
  const float* t2_g    = (const float*)d_in[21];
  const float* t2_beta = (const float*)d_in[22];
  const float* head_W  = (const float*)d_in[23];
  const float* head_b  = (const float*)d_in[24];
  float* out = (float*)d_out;

  float* p = (float*)d_ws;
  float* xn    = p; p += N_ * H_;
  float* buf   = p; p += N_ * H_;
  float* sstat = p; p += 6 * 512;   // 6 stages x (ssum 256 | ssq 256)
  float* xg    = p; p += G_ * 384;
  float* u1    = p; p += G_ * 256;
  float* u2    = p; p += G_ * 128;
  unsigned* up = (unsigned*)p;
  unsigned* xlb  = up; up += (size_t)N_ * 64;
  unsigned* xrb  = up; up += (size_t)N_ * 64;
  unsigned* easb = up; up += (size_t)E_ * 4;
  unsigned short* wpack = (unsigned short*)up; up += 3 * 32768 / 2;
  int* ip = (int*)up;
  int* deg    = ip; ip += N_;
  int* eoff   = ip; ip += N_ + 1;
  int* cursor = ip; ip += N_;
  int* goff   = ip; ip += G_ + 1;
  int* esrc   = ip; ip += E_;
  int* bsum   = ip; ip += 64;
  int* boff   = ip; ip += 64;

#define SSUM(s) (sstat + (s) * 512)
#define SSQ(s)  (sstat + (s) * 512 + 256)

  // ---- build CSR structures + pre-pack weights ----
  hipMemsetAsync(deg, 0, (size_t)N_ * sizeof(int), stream);
  hipMemsetAsync(sstat, 0, 6 * 512 * sizeof(float), stream);
  hist_kernel<<<1024, 256, 0, stream>>>(ei + E_, E_, deg);
  scan_local<<<49, 1024, 0, stream>>>(deg, eoff, bsum, N_);
  scan_bsum<<<1, 64, 0, stream>>>(bsum, boff, 49);
  scan_add<<<49, 1024, 0, stream>>>(eoff, boff, cursor, N_);
  edge_scatter<<<(E_ + 255) / 256, 256, 0, stream>>>(ei, ea, cursor, esrc, easb);
  goff_from_sorted<<<(N_ + 255) / 256, 256, 0, stream>>>(batch, goff);
  pack_weights<<<384, 256, 0, stream>>>(Wl, Wr, wpack);

  // ---- input layer (stats -> stage 0) ----
  in_gemm<<<(N_ + 31) / 32, 256, 0, stream>>>(x, in_W, in_b, buf, SSUM(0), SSQ(0));

  // ---- 3 GATv2 layers ----
  const float rnInv = 1.f / N_;
  const int GT = (N_ + 63) / 64;  // 782
  gemm_mfma<1><<<GT, 256, 0, stream>>>(xn, buf, in_g, in_beta, SSUM(0), SSQ(0), rnInv,
                                       wpack, xlb, xrb);
  agg_csr<<<2048, 256, 0, stream>>>(eoff, esrc, easb, We, att, xlb, xrb, conv_b,
                                    buf, SSUM(1), SSQ(1));
  gemm_mfma<2><<<GT, 256, 0, stream>>>(xn, buf, bn_g, bn_b, SSUM(1), SSQ(1), rnInv,
                                       wpack + 32768, xlb, xrb);
  agg_csr<<<2048, 256, 0, stream>>>(eoff, esrc, easb, We + 8 * H_, att + H_, xlb, xrb,
                                    conv_b + H_, buf, SSUM(2), SSQ(2));
  gemm_mfma<2><<<GT, 256, 0, stream>>>(xn, buf, bn_g + H_, bn_b + H_, SSUM(2), SSQ(2),
                                       rnInv, wpack + 65536, xlb, xrb);
  agg_csr<<<2048, 256, 0, stream>>>(eoff, esrc, easb, We + 16 * H_, att + 2 * H_, xlb, xrb,
                                    conv_b + 2 * H_, buf, SSUM(3), SSQ(3));

  // ---- pooling with fused layer-2 residual (stage 3 stats) ----
  pool_residual<<<G_, 128, 0, stream>>>(goff, xn, buf, bn_g + 2 * H_, bn_b + 2 * H_,
                                        SSUM(3), SSQ(3), rnInv, xg);

  // ---- t1 (stats -> stage 4) ----
  const float rgInv = 1.f / G_;
  mlp_gemm<384, 256><<<G_ / 8, 256, 0, stream>>>(xg, t1_W, t1_b, u1, G_, SSUM(4), SSQ(4));
  apply_bn_relu<<<(G_ * 256 + 255) / 256, 256, 0, stream>>>(u1, u1, t1_g, t1_beta,
                                                            SSUM(4), SSQ(4), rgInv,
                                                            (long)G_ * 256, 255);

  // ---- t2 (stats -> stage 5) ----
  mlp_gemm<256, 128><<<G_ / 8, 128, 0, stream>>>(u1, t2_W, t2_b, u2, G_, SSUM(5), SSQ(5));
  apply_bn_relu<<<(G_ * 128 + 255) / 256, 256, 0, stream>>>(u2, u2, t2_g, t2_beta,
                                                            SSUM(5), SSQ(5), rgInv,
                                                            (long)G_ * 128, 127);

  // ---- head ----
  head_kernel<<<G_, 64, 0, stream>>>(u2, head_W, head_b, out);
#undef SSUM
#undef SSQ
}